// Round 1
// baseline (372.305 us; speedup 1.0000x reference)
//
#include <hip/hip_runtime.h>
#include <math.h>

#define TSTEPS   1000
#define NB       2048
#define NPER     64
#define NATOMS   (NB*NPER)
#define NDIM     64
#define NHID     128
#define NSPEC    100

// ---------------------------------------------------------------------------
// K1: cosine schedule (fp64, matches numpy) + zero the fp64 accumulators.
// betas_t = clip(1 - acp[t+1]/acp[t], 1e-4, 0.999); cumprod via log-space scan.
// Normalization acp/acp[0] cancels in the ratio, so it is omitted.
// ---------------------------------------------------------------------------
__global__ __launch_bounds__(1024) void k_sched(float* __restrict__ sacp,
                                                float* __restrict__ som,
                                                double* __restrict__ accs) {
  __shared__ double sh[1024];
  const int tid = threadIdx.x;
  double lg = 0.0;
  if (tid < TSTEPS) {
    const double PI = 3.14159265358979323846;
    const double s  = 0.008;
    double u0 = (((double)tid     / (double)TSTEPS) + s) / (1.0 + s) * PI * 0.5;
    double u1 = (((double)(tid+1) / (double)TSTEPS) + s) / (1.0 + s) * PI * 0.5;
    double c0 = cos(u0), c1 = cos(u1);
    double beta = 1.0 - (c1*c1)/(c0*c0);
    beta = fmin(fmax(beta, 1e-4), 0.999);
    lg = log(1.0 - beta);
  }
  sh[tid] = lg;
  __syncthreads();
  // inclusive Hillis-Steele scan over 1024 entries
  for (int off = 1; off < 1024; off <<= 1) {
    double add = (tid >= off) ? sh[tid - off] : 0.0;
    __syncthreads();
    sh[tid] += add;
    __syncthreads();
  }
  if (tid < TSTEPS) {
    double cum = exp(sh[tid]);            // alphas_cumprod[tid]
    sacp[tid] = (float)sqrt(cum);
    som[tid]  = (float)sqrt(1.0 - cum);
  }
  if (tid < 4) accs[tid] = 0.0;           // accs re-poisoned each launch -> zero here
}

// ---------------------------------------------------------------------------
// K2: per-crystal PBC repulsion + fused diffusion-MSE partial.
// One block (256 thr) per crystal: 192 threads compute pred_x0 componentwise
// into LDS, then 4096 ordered pairs / 256 threads = 16 pairs each.
// i is wave-uniform (broadcast LDS read); j == lane (stride-3, conflict-free).
// ---------------------------------------------------------------------------
__global__ __launch_bounds__(256) void k_rep(const float* __restrict__ frac,
                                             const float* __restrict__ noise,
                                             const float* __restrict__ pnoise,
                                             const float* __restrict__ lattice,
                                             const int*   __restrict__ tarr,
                                             const float* __restrict__ sacp,
                                             const float* __restrict__ som,
                                             double* __restrict__ accs) {
  __shared__ float f[NPER*3];
  __shared__ float wred[8];
  const int b   = blockIdx.x;
  const int tid = threadIdx.x;
  const int tt  = tarr[b];
  const float sa = sacp[tt];
  const float so = som[tt];
  float msep = 0.0f;
  if (tid < NPER*3) {
    const int gi = b*(NPER*3) + tid;
    float fr = frac[gi], nz = noise[gi], p = pnoise[gi];
    float xt = sa*fr + so*nz;
    xt -= floorf(xt);                     // periodic wrap
    float px = (xt - so*p) / sa;
    px -= floorf(px);                     // wrapped pred_x0
    f[tid] = px;
    float d = p - nz;
    msep = d*d;                           // diffusion MSE partial
  }
  const float* L = lattice + b*9;         // uniform per block -> scalar loads
  const float L00=L[0],L01=L[1],L02=L[2],
              L10=L[3],L11=L[4],L12=L[5],
              L20=L[6],L21=L[7],L22=L[8];
  __syncthreads();
  float rep = 0.0f;
  #pragma unroll 4
  for (int it = 0; it < 16; ++it) {
    int p = it*256 + tid;
    int i = p >> 6;                       // wave-uniform
    int j = p & 63;                       // == lane
    if (i != j) {
      float dx = f[i*3+0] - f[j*3+0]; dx -= rintf(dx);   // minimum image (round-half-even)
      float dy = f[i*3+1] - f[j*3+1]; dy -= rintf(dy);
      float dz = f[i*3+2] - f[j*3+2]; dz -= rintf(dz);
      float cx = dx*L00 + dy*L10 + dz*L20;                // diff @ lattice
      float cy = dx*L01 + dy*L11 + dz*L21;
      float cz = dx*L02 + dy*L12 + dz*L22;
      float dist = sqrtf(cx*cx + cy*cy + cz*cz + 1e-8f);
      float r = 0.8f - dist;
      if (r > 0.0f) rep = fmaf(r, r, rep);
    }
  }
  #pragma unroll
  for (int o = 32; o > 0; o >>= 1) {
    rep  += __shfl_down(rep,  o, 64);
    msep += __shfl_down(msep, o, 64);
  }
  const int lane = tid & 63, w = tid >> 6;
  if (lane == 0) { wred[w] = rep; wred[4+w] = msep; }
  __syncthreads();
  if (tid == 0) {
    double rsum = (double)wred[0] + wred[1] + wred[2] + wred[3];
    double msum = (double)wred[4] + wred[5] + wred[6] + wred[7];
    atomicAdd(&accs[1], rsum);
    atomicAdd(&accs[0], msum);
  }
}

// ---------------------------------------------------------------------------
// K3: species head. One thread per atom, fp32 everywhere (round-1 baseline).
// hid[128] register-resident; W1/W2 indices are wave-uniform -> scalar loads.
// Online log-softmax (branchless) with 4 independent FMA chains per class.
// ---------------------------------------------------------------------------
__global__ __launch_bounds__(256) void k_species(const float* __restrict__ hfin,
                                                 const float* __restrict__ W1,
                                                 const float* __restrict__ b1,
                                                 const float* __restrict__ W2,
                                                 const float* __restrict__ b2,
                                                 const int*   __restrict__ spec,
                                                 double* __restrict__ accs) {
  const int atom = blockIdx.x*256 + threadIdx.x;
  const float4* h4 = reinterpret_cast<const float4*>(hfin + (size_t)atom*NDIM);
  float hid[NHID];
  #pragma unroll
  for (int j = 0; j < NHID; ++j) hid[j] = b1[j];
  #pragma unroll 1
  for (int k4 = 0; k4 < NDIM/4; ++k4) {
    float4 hv = h4[k4];
    const float* w0 = W1 + (k4*4+0)*NHID;
    const float* w1 = W1 + (k4*4+1)*NHID;
    const float* w2 = W1 + (k4*4+2)*NHID;
    const float* w3 = W1 + (k4*4+3)*NHID;
    #pragma unroll
    for (int j = 0; j < NHID; ++j) {
      float a = hid[j];
      a = fmaf(hv.x, w0[j], a);
      a = fmaf(hv.y, w1[j], a);
      a = fmaf(hv.z, w2[j], a);
      a = fmaf(hv.w, w3[j], a);
      hid[j] = a;
    }
  }
  #pragma unroll
  for (int j = 0; j < NHID; ++j) {
    float x = hid[j];
    hid[j] = x / (1.0f + __expf(-x));     // SiLU
  }
  const int tgt = spec[atom];
  float m = -1e30f, ssum = 0.0f, ltgt = 0.0f;
  #pragma unroll 1
  for (int c = 0; c < NSPEC; ++c) {
    float a0=0.f, a1=0.f, a2=0.f, a3=0.f;
    const float* wc = W2 + c;
    #pragma unroll
    for (int j = 0; j < NHID; j += 4) {
      a0 = fmaf(hid[j+0], wc[(j+0)*NSPEC], a0);
      a1 = fmaf(hid[j+1], wc[(j+1)*NSPEC], a1);
      a2 = fmaf(hid[j+2], wc[(j+2)*NSPEC], a2);
      a3 = fmaf(hid[j+3], wc[(j+3)*NSPEC], a3);
    }
    float Lc = ((a0+a1)+(a2+a3)) + b2[c];
    if (c == tgt) ltgt = Lc;
    float mn = fmaxf(m, Lc);
    ssum = ssum*__expf(m - mn) + __expf(Lc - mn);
    m = mn;
  }
  float logp = ltgt - (m + __logf(ssum));
  #pragma unroll
  for (int o = 32; o > 0; o >>= 1) logp += __shfl_down(logp, o, 64);
  __shared__ float wred[4];
  const int lane = threadIdx.x & 63, w = threadIdx.x >> 6;
  if (lane == 0) wred[w] = logp;
  __syncthreads();
  if (threadIdx.x == 0) {
    double t = (double)wred[0] + wred[1] + wred[2] + wred[3];
    atomicAdd(&accs[2], t);
  }
}

// ---------------------------------------------------------------------------
// K4: finalize scalars.
// ---------------------------------------------------------------------------
__global__ void k_fin(const double* __restrict__ accs, float* __restrict__ out) {
  if (threadIdx.x == 0 && blockIdx.x == 0) {
    double mse   = accs[0] / (double)(NATOMS*3);
    double lrep  = accs[1] / (double)NATOMS;     // sum / n / bsz
    double lspec = -accs[2] / (double)NATOMS;
    out[0] = (float)(mse + 5.0*lrep);
    out[1] = (float)lspec;
    out[2] = (float)lrep;
  }
}

extern "C" void kernel_launch(void* const* d_in, const int* in_sizes, int n_in,
                              void* d_out, int out_size, void* d_ws, size_t ws_size,
                              hipStream_t stream) {
  const float* frac    = (const float*)d_in[0];
  const float* noise   = (const float*)d_in[1];
  const float* pnoise  = (const float*)d_in[2];
  const float* hfin    = (const float*)d_in[3];
  const float* lattice = (const float*)d_in[4];
  const float* W1      = (const float*)d_in[5];
  const float* b1      = (const float*)d_in[6];
  const float* W2      = (const float*)d_in[7];
  const float* b2      = (const float*)d_in[8];
  const int*   tarr    = (const int*)d_in[9];
  // d_in[10] = batch_indices (implied by uniform 64-atom groups, unused)
  const int*   spec    = (const int*)d_in[11];
  float* out = (float*)d_out;

  // workspace layout: [0,4KB) sqrt_acp f32, [4KB,8KB) sqrt_om f32,
  //                   [8192, 8192+32) fp64 accumulators {mse, rep, spec}
  float*  sacp = (float*)d_ws;
  float*  som  = sacp + 1024;
  double* accs = (double*)((char*)d_ws + 8192);

  k_sched  <<<dim3(1),          dim3(1024), 0, stream>>>(sacp, som, accs);
  k_species<<<dim3(NATOMS/256), dim3(256),  0, stream>>>(hfin, W1, b1, W2, b2, spec, accs);
  k_rep    <<<dim3(NB),         dim3(256),  0, stream>>>(frac, noise, pnoise, lattice,
                                                         tarr, sacp, som, accs);
  k_fin    <<<dim3(1),          dim3(64),   0, stream>>>(accs, out);
}

// Round 2
// 213.880 us; speedup vs baseline: 1.7407x; 1.7407x over previous
//
#include <hip/hip_runtime.h>
#include <math.h>

#define TSTEPS   1000
#define NB       2048
#define NPER     64
#define NATOMS   (NB*NPER)
#define NDIM     64
#define NHID     128
#define NSPEC    100
#define NSPECP   112            // padded to 7*16 for MFMA N-tiles
#define W1T_LD   72             // 64 + 8 bf16 pad  -> bank shift 4/row, 16B aligned
#define W2T_LD   136            // 128 + 8 bf16 pad
#define H_LD     136
#define W1T_BYTES (NHID*W1T_LD*2)     // 18432
#define W2T_BYTES (NSPECP*W2T_LD*2)   // 30464
#define H_BYTES   (64*H_LD*2)         // 17408

typedef __attribute__((ext_vector_type(8))) short bf16x8;
typedef __attribute__((ext_vector_type(4))) float f32x4;

// fp32 -> bf16 bits, round-to-nearest-even (branch-free; inputs are finite)
__device__ inline short f2bf(float x) {
  unsigned u = __builtin_bit_cast(unsigned, x);
  u += 0x7fffu + ((u >> 16) & 1u);
  return (short)(u >> 16);
}

// ---------------------------------------------------------------------------
// K1: cosine schedule (fp64, matches numpy) + zero accumulators + build
// transposed bf16 weight images (W1T [128][72], W2T [112][136]) in workspace.
// ---------------------------------------------------------------------------
__global__ __launch_bounds__(1024) void k_sched(float* __restrict__ sacp,
                                                float* __restrict__ som,
                                                double* __restrict__ accs,
                                                const float* __restrict__ W1,
                                                const float* __restrict__ W2,
                                                unsigned short* __restrict__ w1t,
                                                unsigned short* __restrict__ w2t) {
  __shared__ double sh[1024];
  const int tid = threadIdx.x;
  double lg = 0.0;
  if (tid < TSTEPS) {
    const double PI = 3.14159265358979323846;
    const double s  = 0.008;
    double u0 = (((double)tid     / (double)TSTEPS) + s) / (1.0 + s) * PI * 0.5;
    double u1 = (((double)(tid+1) / (double)TSTEPS) + s) / (1.0 + s) * PI * 0.5;
    double c0 = cos(u0), c1 = cos(u1);
    double beta = 1.0 - (c1*c1)/(c0*c0);
    beta = fmin(fmax(beta, 1e-4), 0.999);
    lg = log(1.0 - beta);
  }
  sh[tid] = lg;
  __syncthreads();
  for (int off = 1; off < 1024; off <<= 1) {   // inclusive log-space scan
    double add = (tid >= off) ? sh[tid - off] : 0.0;
    __syncthreads();
    sh[tid] += add;
    __syncthreads();
  }
  if (tid < TSTEPS) {
    double cum = exp(sh[tid]);
    sacp[tid] = (float)sqrt(cum);
    som[tid]  = (float)sqrt(1.0 - cum);
  }
  if (tid < 4) accs[tid] = 0.0;
  // W1T: [n=0..127][k=0..63], bf16, row stride 72
  for (int i = tid; i < NDIM*NHID; i += 1024) {
    int n = i & (NHID-1), k = i >> 7;
    w1t[n*W1T_LD + k] = (unsigned short)f2bf(W1[k*NHID + n]);
  }
  // W2T: [n=0..111][k=0..127], bf16, row stride 136; pad classes = 0 (masked later)
  for (int i = tid; i < NSPECP*NHID; i += 1024) {
    int n = i % NSPECP, k = i / NSPECP;
    w2t[n*W2T_LD + k] = (unsigned short)(n < NSPEC ? f2bf(W2[k*NSPEC + n]) : 0);
  }
}

// ---------------------------------------------------------------------------
// K2: species head via bf16 MFMA. Block = 64 atoms, 4 waves x 16-row slab.
// GEMM1 A-frags straight from global fp32 (each element read once).
// LDS phases: [0,30464) = W1T then W2T (aliased), [30464,+17408) = H bf16.
// ---------------------------------------------------------------------------
__global__ __launch_bounds__(256) void k_species(const float* __restrict__ hfin,
                                                 const float* __restrict__ b1,
                                                 const float* __restrict__ b2,
                                                 const int*   __restrict__ spec,
                                                 const unsigned short* __restrict__ w1t,
                                                 const unsigned short* __restrict__ w2t,
                                                 double* __restrict__ accs) {
  __shared__ __attribute__((aligned(16))) unsigned char lds[W2T_BYTES + H_BYTES];
  __shared__ float wred[4];
  const int tid  = threadIdx.x;
  const int wave = tid >> 6, lane = tid & 63;
  const int l15  = lane & 15, quad = lane >> 4;
  const int atomBase = blockIdx.x * 64;
  const int slabBase = atomBase + wave * 16;

  // A-fragments for GEMM1: X[slabBase+l15][k = kk*32 + quad*8 + j]
  bf16x8 aF[2];
  {
    const float* rp = hfin + (size_t)(slabBase + l15) * NDIM;
    #pragma unroll
    for (int kk = 0; kk < 2; ++kk) {
      const float4 p = *(const float4*)(rp + kk*32 + quad*8);
      const float4 q = *(const float4*)(rp + kk*32 + quad*8 + 4);
      bf16x8 a;
      a[0]=f2bf(p.x); a[1]=f2bf(p.y); a[2]=f2bf(p.z); a[3]=f2bf(p.w);
      a[4]=f2bf(q.x); a[5]=f2bf(q.y); a[6]=f2bf(q.z); a[7]=f2bf(q.w);
      aF[kk] = a;
    }
  }
  // stage W1T
  for (int off = tid*16; off < W1T_BYTES; off += 256*16)
    *(uint4*)(lds + off) = *(const uint4*)((const unsigned char*)w1t + off);
  __syncthreads();

  // GEMM1: H_pre[64 x 128] = X @ W1
  f32x4 acc1[8];
  #pragma unroll
  for (int nt = 0; nt < 8; ++nt) acc1[nt] = (f32x4){0.f,0.f,0.f,0.f};
  #pragma unroll
  for (int nt = 0; nt < 8; ++nt) {
    #pragma unroll
    for (int kk = 0; kk < 2; ++kk) {
      bf16x8 b = *(const bf16x8*)(lds + ((nt*16 + l15)*W1T_LD + kk*32 + quad*8)*2);
      acc1[nt] = __builtin_amdgcn_mfma_f32_16x16x32_bf16(aF[kk], b, acc1[nt], 0, 0, 0);
    }
  }
  // epilogue1: +b1, SiLU, bf16 -> H LDS (D-layout -> A-layout via LDS round-trip)
  #pragma unroll
  for (int nt = 0; nt < 8; ++nt) {
    const int   n    = nt*16 + l15;
    const float bias = b1[n];
    #pragma unroll
    for (int r = 0; r < 4; ++r) {
      float x  = acc1[nt][r] + bias;
      float sl = x / (1.0f + __expf(-x));
      *(short*)(lds + W2T_BYTES + ((wave*16 + quad*4 + r)*H_LD + n)*2) = f2bf(sl);
    }
  }
  __syncthreads();
  // stage W2T over the W1T region
  for (int off = tid*16; off < W2T_BYTES; off += 256*16)
    *(uint4*)(lds + off) = *(const uint4*)((const unsigned char*)w2t + off);
  __syncthreads();

  // GEMM2: logits[64 x 112] = H @ W2
  bf16x8 a2[4];
  #pragma unroll
  for (int kk = 0; kk < 4; ++kk)
    a2[kk] = *(const bf16x8*)(lds + W2T_BYTES + ((wave*16 + l15)*H_LD + kk*32 + quad*8)*2);
  f32x4 acc2[7];
  #pragma unroll
  for (int nt = 0; nt < 7; ++nt) acc2[nt] = (f32x4){0.f,0.f,0.f,0.f};
  #pragma unroll
  for (int nt = 0; nt < 7; ++nt) {
    #pragma unroll
    for (int kk = 0; kk < 4; ++kk) {
      bf16x8 b = *(const bf16x8*)(lds + ((nt*16 + l15)*W2T_LD + kk*32 + quad*8)*2);
      acc2[nt] = __builtin_amdgcn_mfma_f32_16x16x32_bf16(a2[kk], b, acc2[nt], 0, 0, 0);
    }
  }
  // epilogue2: +b2, mask pad, per-row log-softmax (row's 112 logits live in one quad)
  float b2v[7];
  #pragma unroll
  for (int nt = 0; nt < 7; ++nt) {
    int n = nt*16 + l15;
    b2v[nt] = (n < NSPEC) ? b2[n] : 0.0f;
  }
  float lsum = 0.0f;
  #pragma unroll
  for (int r = 0; r < 4; ++r) {
    const int tgt = spec[atomBase + wave*16 + quad*4 + r];
    float val[7], mx = -1e30f;
    #pragma unroll
    for (int nt = 0; nt < 7; ++nt) {
      int n = nt*16 + l15;
      float v = acc2[nt][r] + b2v[nt];
      v = (n < NSPEC) ? v : -1e30f;
      val[nt] = v;
      mx = fmaxf(mx, v);
    }
    #pragma unroll
    for (int d = 1; d < 16; d <<= 1) mx = fmaxf(mx, __shfl_xor(mx, d, 64));
    float s = 0.0f, lt = 0.0f;
    #pragma unroll
    for (int nt = 0; nt < 7; ++nt) {
      s += __expf(val[nt] - mx);
      if (nt*16 + l15 == tgt) lt = val[nt];
    }
    #pragma unroll
    for (int d = 1; d < 16; d <<= 1) { s += __shfl_xor(s, d, 64); lt += __shfl_xor(lt, d, 64); }
    if (l15 == 0) lsum += lt - mx - __logf(s);
  }
  lsum += __shfl_down(lsum, 32, 64);
  lsum += __shfl_down(lsum, 16, 64);
  if (lane == 0) wred[wave] = lsum;
  __syncthreads();
  if (tid == 0) {
    double t = (double)wred[0] + wred[1] + wred[2] + wred[3];
    atomicAdd(&accs[2], t);
  }
}

// ---------------------------------------------------------------------------
// K3: per-crystal PBC repulsion + fused diffusion-MSE partial (unchanged).
// ---------------------------------------------------------------------------
__global__ __launch_bounds__(256) void k_rep(const float* __restrict__ frac,
                                             const float* __restrict__ noise,
                                             const float* __restrict__ pnoise,
                                             const float* __restrict__ lattice,
                                             const int*   __restrict__ tarr,
                                             const float* __restrict__ sacp,
                                             const float* __restrict__ som,
                                             double* __restrict__ accs) {
  __shared__ float f[NPER*3];
  __shared__ float wred[8];
  const int b   = blockIdx.x;
  const int tid = threadIdx.x;
  const int tt  = tarr[b];
  const float sa = sacp[tt];
  const float so = som[tt];
  float msep = 0.0f;
  if (tid < NPER*3) {
    const int gi = b*(NPER*3) + tid;
    float fr = frac[gi], nz = noise[gi], p = pnoise[gi];
    float xt = sa*fr + so*nz;
    xt -= floorf(xt);
    float px = (xt - so*p) / sa;
    px -= floorf(px);
    f[tid] = px;
    float d = p - nz;
    msep = d*d;
  }
  const float* L = lattice + b*9;
  const float L00=L[0],L01=L[1],L02=L[2],
              L10=L[3],L11=L[4],L12=L[5],
              L20=L[6],L21=L[7],L22=L[8];
  __syncthreads();
  float rep = 0.0f;
  #pragma unroll 4
  for (int it = 0; it < 16; ++it) {
    int p = it*256 + tid;
    int i = p >> 6;
    int j = p & 63;
    if (i != j) {
      float dx = f[i*3+0] - f[j*3+0]; dx -= rintf(dx);
      float dy = f[i*3+1] - f[j*3+1]; dy -= rintf(dy);
      float dz = f[i*3+2] - f[j*3+2]; dz -= rintf(dz);
      float cx = dx*L00 + dy*L10 + dz*L20;
      float cy = dx*L01 + dy*L11 + dz*L21;
      float cz = dx*L02 + dy*L12 + dz*L22;
      float dist = sqrtf(cx*cx + cy*cy + cz*cz + 1e-8f);
      float r = 0.8f - dist;
      if (r > 0.0f) rep = fmaf(r, r, rep);
    }
  }
  #pragma unroll
  for (int o = 32; o > 0; o >>= 1) {
    rep  += __shfl_down(rep,  o, 64);
    msep += __shfl_down(msep, o, 64);
  }
  const int lane = tid & 63, w = tid >> 6;
  if (lane == 0) { wred[w] = rep; wred[4+w] = msep; }
  __syncthreads();
  if (tid == 0) {
    double rsum = (double)wred[0] + wred[1] + wred[2] + wred[3];
    double msum = (double)wred[4] + wred[5] + wred[6] + wred[7];
    atomicAdd(&accs[1], rsum);
    atomicAdd(&accs[0], msum);
  }
}

__global__ void k_fin(const double* __restrict__ accs, float* __restrict__ out) {
  if (threadIdx.x == 0 && blockIdx.x == 0) {
    double mse   = accs[0] / (double)(NATOMS*3);
    double lrep  = accs[1] / (double)NATOMS;
    double lspec = -accs[2] / (double)NATOMS;
    out[0] = (float)(mse + 5.0*lrep);
    out[1] = (float)lspec;
    out[2] = (float)lrep;
  }
}

extern "C" void kernel_launch(void* const* d_in, const int* in_sizes, int n_in,
                              void* d_out, int out_size, void* d_ws, size_t ws_size,
                              hipStream_t stream) {
  const float* frac    = (const float*)d_in[0];
  const float* noise   = (const float*)d_in[1];
  const float* pnoise  = (const float*)d_in[2];
  const float* hfin    = (const float*)d_in[3];
  const float* lattice = (const float*)d_in[4];
  const float* W1      = (const float*)d_in[5];
  const float* b1      = (const float*)d_in[6];
  const float* W2      = (const float*)d_in[7];
  const float* b2      = (const float*)d_in[8];
  const int*   tarr    = (const int*)d_in[9];
  const int*   spec    = (const int*)d_in[11];
  float* out = (float*)d_out;

  // ws layout: [0,4K) sacp f32 | [4K,8K) som f32 | [8192,+32) fp64 accs
  //            [8320,+18432) W1T bf16 | [26752,+30464) W2T bf16   (57216 B total)
  float*  sacp = (float*)d_ws;
  float*  som  = sacp + 1024;
  double* accs = (double*)((char*)d_ws + 8192);
  unsigned short* w1t = (unsigned short*)((char*)d_ws + 8320);
  unsigned short* w2t = (unsigned short*)((char*)d_ws + 26752);

  k_sched  <<<dim3(1),    dim3(1024), 0, stream>>>(sacp, som, accs, W1, W2, w1t, w2t);
  k_species<<<dim3(NB),   dim3(256),  0, stream>>>(hfin, b1, b2, spec, w1t, w2t, accs);
  k_rep    <<<dim3(NB),   dim3(256),  0, stream>>>(frac, noise, pnoise, lattice,
                                                   tarr, sacp, som, accs);
  k_fin    <<<dim3(1),    dim3(64),   0, stream>>>(accs, out);
}

// Round 3
// 159.852 us; speedup vs baseline: 2.3291x; 1.3380x over previous
//
#include <hip/hip_runtime.h>
#include <math.h>

#define TSTEPS   1000
#define NB       2048
#define NPER     64
#define NATOMS   (NB*NPER)
#define NDIM     64
#define NHID     128
#define NSPEC    100
#define NSPECP   112            // padded to 7*16 for MFMA N-tiles
#define W1T_LD   72             // 64 + 8 bf16 pad  -> bank shift 4/row, 16B aligned
#define W2T_LD   136            // 128 + 8 bf16 pad
#define H_LD     136
#define W1T_BYTES (NHID*W1T_LD*2)     // 18432
#define W2T_BYTES (NSPECP*W2T_LD*2)   // 30464
#define H_BYTES   (64*H_LD*2)         // 17408

typedef __attribute__((ext_vector_type(8))) short bf16x8;
typedef __attribute__((ext_vector_type(4))) float f32x4;

// fp32 -> bf16 bits, round-to-nearest-even (branch-free; inputs are finite)
__device__ inline short f2bf(float x) {
  unsigned u = __builtin_bit_cast(unsigned, x);
  u += 0x7fffu + ((u >> 16) & 1u);
  return (short)(u >> 16);
}

// ---------------------------------------------------------------------------
// K1: cosine schedule (fp64, matches numpy) + transposed bf16 weight images.
// ---------------------------------------------------------------------------
__global__ __launch_bounds__(1024) void k_sched(float* __restrict__ sacp,
                                                float* __restrict__ som,
                                                const float* __restrict__ W1,
                                                const float* __restrict__ W2,
                                                unsigned short* __restrict__ w1t,
                                                unsigned short* __restrict__ w2t) {
  __shared__ double sh[1024];
  const int tid = threadIdx.x;
  double lg = 0.0;
  if (tid < TSTEPS) {
    const double PI = 3.14159265358979323846;
    const double s  = 0.008;
    double u0 = (((double)tid     / (double)TSTEPS) + s) / (1.0 + s) * PI * 0.5;
    double u1 = (((double)(tid+1) / (double)TSTEPS) + s) / (1.0 + s) * PI * 0.5;
    double c0 = cos(u0), c1 = cos(u1);
    double beta = 1.0 - (c1*c1)/(c0*c0);
    beta = fmin(fmax(beta, 1e-4), 0.999);
    lg = log(1.0 - beta);
  }
  sh[tid] = lg;
  __syncthreads();
  for (int off = 1; off < 1024; off <<= 1) {   // inclusive log-space scan
    double add = (tid >= off) ? sh[tid - off] : 0.0;
    __syncthreads();
    sh[tid] += add;
    __syncthreads();
  }
  if (tid < TSTEPS) {
    double cum = exp(sh[tid]);
    sacp[tid] = (float)sqrt(cum);
    som[tid]  = (float)sqrt(1.0 - cum);
  }
  // W1T: [n=0..127][k=0..63], bf16, row stride 72
  for (int i = tid; i < NDIM*NHID; i += 1024) {
    int n = i & (NHID-1), k = i >> 7;
    w1t[n*W1T_LD + k] = (unsigned short)f2bf(W1[k*NHID + n]);
  }
  // W2T: [n=0..111][k=0..127], bf16, row stride 136; pad classes = 0 (masked later)
  for (int i = tid; i < NSPECP*NHID; i += 1024) {
    int n = i % NSPECP, k = i / NSPECP;
    w2t[n*W2T_LD + k] = (unsigned short)(n < NSPEC ? f2bf(W2[k*NSPEC + n]) : 0);
  }
}

// ---------------------------------------------------------------------------
// K2: fused species head (bf16 MFMA) + PBC repulsion + diffusion MSE.
// Block = 1 crystal (64 atoms), 256 threads. NO global atomics: per-block
// partials are written to distinct ws slots (deterministic, no serialization).
// Rep inputs are loaded in the prologue so their latency hides under GEMMs.
// ---------------------------------------------------------------------------
__global__ __launch_bounds__(256) void k_main(const float* __restrict__ hfin,
                                              const float* __restrict__ b1,
                                              const float* __restrict__ b2,
                                              const int*   __restrict__ spec,
                                              const unsigned short* __restrict__ w1t,
                                              const unsigned short* __restrict__ w2t,
                                              const float* __restrict__ frac,
                                              const float* __restrict__ noise,
                                              const float* __restrict__ pnoise,
                                              const float* __restrict__ lattice,
                                              const int*   __restrict__ tarr,
                                              const float* __restrict__ sacp,
                                              const float* __restrict__ som,
                                              float* __restrict__ mseP,
                                              float* __restrict__ repP,
                                              float* __restrict__ specP) {
  __shared__ __attribute__((aligned(16))) unsigned char lds[W2T_BYTES + H_BYTES];
  __shared__ float wred[8];
  const int tid  = threadIdx.x;
  const int wave = tid >> 6, lane = tid & 63;
  const int l15  = lane & 15, quad = lane >> 4;
  const int b    = blockIdx.x;
  const int atomBase = b * 64;
  const int slabBase = atomBase + wave * 16;

  // ---- rep prologue: wrapped pred_x0 component + MSE partial (192 threads) ----
  const int tt = tarr[b];
  const float sa = sacp[tt], so = som[tt];
  float px = 0.0f, msep = 0.0f;
  if (tid < NPER*3) {
    const int gi = b*(NPER*3) + tid;
    float fr = frac[gi], nz = noise[gi], p = pnoise[gi];
    float xt = sa*fr + so*nz;
    xt -= floorf(xt);                        // periodic wrap
    px = (xt - so*p) / sa;
    px -= floorf(px);                        // wrapped pred_x0
    float d = p - nz;
    msep = d*d;
  }

  // ---- species GEMM1 A-frags straight from global fp32 ----
  bf16x8 aF[2];
  {
    const float* rp = hfin + (size_t)(slabBase + l15) * NDIM;
    #pragma unroll
    for (int kk = 0; kk < 2; ++kk) {
      const float4 p = *(const float4*)(rp + kk*32 + quad*8);
      const float4 q = *(const float4*)(rp + kk*32 + quad*8 + 4);
      bf16x8 a;
      a[0]=f2bf(p.x); a[1]=f2bf(p.y); a[2]=f2bf(p.z); a[3]=f2bf(p.w);
      a[4]=f2bf(q.x); a[5]=f2bf(q.y); a[6]=f2bf(q.z); a[7]=f2bf(q.w);
      aF[kk] = a;
    }
  }
  // stage W1T
  for (int off = tid*16; off < W1T_BYTES; off += 256*16)
    *(uint4*)(lds + off) = *(const uint4*)((const unsigned char*)w1t + off);
  __syncthreads();

  // GEMM1: H_pre[64 x 128] = X @ W1
  f32x4 acc1[8];
  #pragma unroll
  for (int nt = 0; nt < 8; ++nt) acc1[nt] = (f32x4){0.f,0.f,0.f,0.f};
  #pragma unroll
  for (int nt = 0; nt < 8; ++nt) {
    #pragma unroll
    for (int kk = 0; kk < 2; ++kk) {
      bf16x8 bb = *(const bf16x8*)(lds + ((nt*16 + l15)*W1T_LD + kk*32 + quad*8)*2);
      acc1[nt] = __builtin_amdgcn_mfma_f32_16x16x32_bf16(aF[kk], bb, acc1[nt], 0, 0, 0);
    }
  }
  // epilogue1: +b1, SiLU, bf16 -> H LDS (D-layout -> A-layout via LDS round-trip)
  #pragma unroll
  for (int nt = 0; nt < 8; ++nt) {
    const int   n    = nt*16 + l15;
    const float bias = b1[n];
    #pragma unroll
    for (int r = 0; r < 4; ++r) {
      float x  = acc1[nt][r] + bias;
      float sl = x / (1.0f + __expf(-x));
      *(short*)(lds + W2T_BYTES + ((wave*16 + quad*4 + r)*H_LD + n)*2) = f2bf(sl);
    }
  }
  __syncthreads();
  // stage W2T over the W1T region
  for (int off = tid*16; off < W2T_BYTES; off += 256*16)
    *(uint4*)(lds + off) = *(const uint4*)((const unsigned char*)w2t + off);
  __syncthreads();

  // GEMM2: logits[64 x 112] = H @ W2
  bf16x8 a2[4];
  #pragma unroll
  for (int kk = 0; kk < 4; ++kk)
    a2[kk] = *(const bf16x8*)(lds + W2T_BYTES + ((wave*16 + l15)*H_LD + kk*32 + quad*8)*2);
  f32x4 acc2[7];
  #pragma unroll
  for (int nt = 0; nt < 7; ++nt) acc2[nt] = (f32x4){0.f,0.f,0.f,0.f};
  #pragma unroll
  for (int nt = 0; nt < 7; ++nt) {
    #pragma unroll
    for (int kk = 0; kk < 4; ++kk) {
      bf16x8 bb = *(const bf16x8*)(lds + ((nt*16 + l15)*W2T_LD + kk*32 + quad*8)*2);
      acc2[nt] = __builtin_amdgcn_mfma_f32_16x16x32_bf16(a2[kk], bb, acc2[nt], 0, 0, 0);
    }
  }
  // epilogue2: +b2, mask pad, per-row log-softmax (row's 112 logits in one quad)
  float b2v[7];
  #pragma unroll
  for (int nt = 0; nt < 7; ++nt) {
    int n = nt*16 + l15;
    b2v[nt] = (n < NSPEC) ? b2[n] : 0.0f;
  }
  float lsum = 0.0f;
  #pragma unroll
  for (int r = 0; r < 4; ++r) {
    const int tgt = spec[atomBase + wave*16 + quad*4 + r];
    float val[7], mx = -1e30f;
    #pragma unroll
    for (int nt = 0; nt < 7; ++nt) {
      int n = nt*16 + l15;
      float v = acc2[nt][r] + b2v[nt];
      v = (n < NSPEC) ? v : -1e30f;
      val[nt] = v;
      mx = fmaxf(mx, v);
    }
    #pragma unroll
    for (int d = 1; d < 16; d <<= 1) mx = fmaxf(mx, __shfl_xor(mx, d, 64));
    float s = 0.0f, lt = 0.0f;
    #pragma unroll
    for (int nt = 0; nt < 7; ++nt) {
      s += __expf(val[nt] - mx);
      if (nt*16 + l15 == tgt) lt = val[nt];
    }
    #pragma unroll
    for (int d = 1; d < 16; d <<= 1) { s += __shfl_xor(s, d, 64); lt += __shfl_xor(lt, d, 64); }
    if (l15 == 0) lsum += lt - mx - __logf(s);
  }
  lsum += __shfl_down(lsum, 32, 64);
  lsum += __shfl_down(lsum, 16, 64);
  if (lane == 0) wred[wave] = lsum;
  __syncthreads();
  if (tid == 0) specP[b] = wred[0] + wred[1] + wred[2] + wred[3];

  // ---- repulsion phase: reuse lds[0..768) for f[] ----
  __syncthreads();                           // all species LDS reads + wred read done
  float* f = (float*)lds;
  if (tid < NPER*3) f[tid] = px;
  __syncthreads();
  const float* L = lattice + b*9;            // uniform per block -> scalar loads
  const float L00=L[0],L01=L[1],L02=L[2],
              L10=L[3],L11=L[4],L12=L[5],
              L20=L[6],L21=L[7],L22=L[8];
  float rep = 0.0f;
  #pragma unroll 4
  for (int it = 0; it < 16; ++it) {
    const int i = it*4 + wave;               // wave-uniform
    const int j = lane;
    if (i != j) {
      float dx = f[i*3+0] - f[j*3+0]; dx -= rintf(dx);   // minimum image
      float dy = f[i*3+1] - f[j*3+1]; dy -= rintf(dy);
      float dz = f[i*3+2] - f[j*3+2]; dz -= rintf(dz);
      float cx = dx*L00 + dy*L10 + dz*L20;
      float cy = dx*L01 + dy*L11 + dz*L21;
      float cz = dx*L02 + dy*L12 + dz*L22;
      float dist = sqrtf(cx*cx + cy*cy + cz*cz + 1e-8f);
      float r = 0.8f - dist;
      if (r > 0.0f) rep = fmaf(r, r, rep);
    }
  }
  #pragma unroll
  for (int o = 32; o > 0; o >>= 1) {
    rep  += __shfl_down(rep,  o, 64);
    msep += __shfl_down(msep, o, 64);
  }
  if (lane == 0) { wred[wave] = rep; wred[4+wave] = msep; }
  __syncthreads();
  if (tid == 0) {
    repP[b] = wred[0] + wred[1] + wred[2] + wred[3];
    mseP[b] = wred[4] + wred[5] + wred[6] + wred[7];
  }
}

// ---------------------------------------------------------------------------
// K3: deterministic fp64 reduction of per-block partials -> 3 scalars.
// ---------------------------------------------------------------------------
__global__ __launch_bounds__(1024) void k_fin(const float* __restrict__ mseP,
                                              const float* __restrict__ repP,
                                              const float* __restrict__ specP,
                                              float* __restrict__ out) {
  __shared__ double sh[48];
  const int tid = threadIdx.x;
  double m = 0.0, r = 0.0, s = 0.0;
  for (int i = tid; i < NB; i += 1024) {
    m += (double)mseP[i];
    r += (double)repP[i];
    s += (double)specP[i];
  }
  #pragma unroll
  for (int o = 32; o > 0; o >>= 1) {
    m += __shfl_down(m, o, 64);
    r += __shfl_down(r, o, 64);
    s += __shfl_down(s, o, 64);
  }
  const int w = tid >> 6, lane = tid & 63;
  if (lane == 0) { sh[w] = m; sh[16+w] = r; sh[32+w] = s; }
  __syncthreads();
  if (tid == 0) {
    double M=0, R=0, S=0;
    for (int i = 0; i < 16; ++i) { M += sh[i]; R += sh[16+i]; S += sh[32+i]; }
    double mse   = M / (double)(NATOMS*3);
    double lrep  = R / (double)NATOMS;
    double lspec = -S / (double)NATOMS;
    out[0] = (float)(mse + 5.0*lrep);
    out[1] = (float)lspec;
    out[2] = (float)lrep;
  }
}

extern "C" void kernel_launch(void* const* d_in, const int* in_sizes, int n_in,
                              void* d_out, int out_size, void* d_ws, size_t ws_size,
                              hipStream_t stream) {
  const float* frac    = (const float*)d_in[0];
  const float* noise   = (const float*)d_in[1];
  const float* pnoise  = (const float*)d_in[2];
  const float* hfin    = (const float*)d_in[3];
  const float* lattice = (const float*)d_in[4];
  const float* W1      = (const float*)d_in[5];
  const float* b1      = (const float*)d_in[6];
  const float* W2      = (const float*)d_in[7];
  const float* b2      = (const float*)d_in[8];
  const int*   tarr    = (const int*)d_in[9];
  const int*   spec    = (const int*)d_in[11];
  float* out = (float*)d_out;

  // ws layout: [0,4K) sacp | [4K,8K) som | [8192,+18432) W1T | [26624,+30464) W2T
  //            [57088,+8192) mseP | [65280,+8192) repP | [73472,+8192) specP
  float*  sacp = (float*)d_ws;
  float*  som  = sacp + 1024;
  unsigned short* w1t = (unsigned short*)((char*)d_ws + 8192);
  unsigned short* w2t = (unsigned short*)((char*)d_ws + 26624);
  float* mseP  = (float*)((char*)d_ws + 57088);
  float* repP  = (float*)((char*)d_ws + 65280);
  float* specP = (float*)((char*)d_ws + 73472);

  k_sched<<<dim3(1),  dim3(1024), 0, stream>>>(sacp, som, W1, W2, w1t, w2t);
  k_main <<<dim3(NB), dim3(256),  0, stream>>>(hfin, b1, b2, spec, w1t, w2t,
                                               frac, noise, pnoise, lattice,
                                               tarr, sacp, som, mseP, repP, specP);
  k_fin  <<<dim3(1),  dim3(1024), 0, stream>>>(mseP, repP, specP, out);
}

// Round 4
// 137.064 us; speedup vs baseline: 2.7163x; 1.1663x over previous
//
#include <hip/hip_runtime.h>
#include <math.h>

#define TSTEPS   1000
#define NB       2048
#define NPER     64
#define NATOMS   (NB*NPER)
#define NDIM     64
#define NHID     128
#define NSPEC    100
#define H_LD     136                  // shorts per atom row: 128 + 8 pad (write ~4-way, read conflict-free)
#define H_LDS_SHORTS (64*H_LD)        // 17408 B

typedef __attribute__((ext_vector_type(8))) short bf16x8;
typedef __attribute__((ext_vector_type(4))) float f32x4;

// fp32 -> bf16 bits, round-to-nearest-even (finite inputs)
__device__ inline short f2bf(float x) {
  unsigned u = __builtin_bit_cast(unsigned, x);
  u += 0x7fffu + ((u >> 16) & 1u);
  return (short)(u >> 16);
}

// ---------------------------------------------------------------------------
// K1 (12 blocks x 256): block 0 = cosine schedule (fp64, 4 t/thread, one
// 256-wide LDS scan); blocks 1-4 = W1 fragment image; blocks 5-11 = W2 image.
// Fragment order: chunk c=(tile*64+lane), 8 shorts each -> k_main reads
// weights as perfectly-coalesced 16B/lane straight from global (L1-broadcast).
//   w1f: A-frag W1T[m=nt*16+l15][k=kk*32+q*8+j], tile = nt*2+kk  (16 tiles)
//   w2f: A-frag W2T[cls=nt*16+l15][k=kk*32+q*8+j], tile = nt*4+kk (28 tiles)
// ---------------------------------------------------------------------------
__global__ __launch_bounds__(256) void k_sched(float* __restrict__ sacp,
                                               float* __restrict__ som,
                                               const float* __restrict__ W1,
                                               const float* __restrict__ W2,
                                               unsigned short* __restrict__ w1f,
                                               unsigned short* __restrict__ w2f) {
  const int tid = threadIdx.x, blk = blockIdx.x;
  if (blk == 0) {
    __shared__ double sh[256];
    const double PI = 3.14159265358979323846, s = 0.008;
    const int t0 = tid * 4;
    double lg[4], loc = 0.0;
    if (t0 < TSTEPS) {
      double c[5];
      #pragma unroll
      for (int i = 0; i < 5; ++i) {
        double u = (((double)(t0 + i) / (double)TSTEPS) + s) / (1.0 + s) * PI * 0.5;
        c[i] = cos(u);
      }
      #pragma unroll
      for (int i = 0; i < 4; ++i) {
        double beta = 1.0 - (c[i+1]*c[i+1]) / (c[i]*c[i]);
        beta = fmin(fmax(beta, 1e-4), 0.999);
        lg[i] = log(1.0 - beta);
        loc += lg[i];
      }
    }
    sh[tid] = loc;
    __syncthreads();
    for (int off = 1; off < 256; off <<= 1) {     // inclusive scan of thread sums
      double add = (tid >= off) ? sh[tid - off] : 0.0;
      __syncthreads();
      sh[tid] += add;
      __syncthreads();
    }
    if (t0 < TSTEPS) {
      double run = sh[tid] - loc;                 // exclusive prefix
      #pragma unroll
      for (int i = 0; i < 4; ++i) {
        run += lg[i];
        double cum = exp(run);                    // alphas_cumprod[t0+i]
        sacp[t0+i] = (float)sqrt(cum);
        som[t0+i]  = (float)sqrt(1.0 - cum);
      }
    }
  } else if (blk <= 4) {
    const int c0 = (blk - 1) * 256 + tid;         // chunk in [0,1024)
    const int lane = c0 & 63, t = c0 >> 6;        // t in [0,16)
    const int kk = t & 1, nt = t >> 1;
    const int q = lane >> 4, l15 = lane & 15;
    __attribute__((aligned(16))) unsigned short v[8];
    #pragma unroll
    for (int j = 0; j < 8; ++j) {
      int k = kk*32 + q*8 + j;
      v[j] = (unsigned short)f2bf(W1[k*NHID + nt*16 + l15]);
    }
    *(uint4*)(w1f + (size_t)c0*8) = *(const uint4*)v;
  } else {
    for (int c0 = (blk - 5) * 256 + tid; c0 < 3584; c0 += 1792) {  // 28 tiles
      const int lane = c0 & 63, t = c0 >> 6;      // t in [0,56)
      const int kk = t & 3, nt = t >> 2;
      const int q = lane >> 4, l15 = lane & 15;
      const int cls = nt*16 + l15;
      __attribute__((aligned(16))) unsigned short v[8];
      #pragma unroll
      for (int j = 0; j < 8; ++j) {
        int k = kk*32 + q*8 + j;
        v[j] = (cls < NSPEC) ? (unsigned short)f2bf(W2[k*NSPEC + cls]) : 0;
      }
      *(uint4*)(w2f + (size_t)c0*8) = *(const uint4*)v;
    }
  }
}

// ---------------------------------------------------------------------------
// K2: fused species head + repulsion + MSE. Block = 1 crystal, 256 threads.
// Swapped-operand MFMA: D = W-frag(A) x X-frag(B) -> D cols = atoms (l15).
// Weights read directly from global frag images (no LDS staging, no restage).
// Only LDS: H (17.4KB, b64 writes / b128 reads) + f[] + wred. 2 barriers.
// ---------------------------------------------------------------------------
__global__ __launch_bounds__(256, 4) void k_main(const float* __restrict__ hfin,
                                                 const float* __restrict__ b1,
                                                 const float* __restrict__ b2,
                                                 const int*   __restrict__ spec,
                                                 const unsigned short* __restrict__ w1f,
                                                 const unsigned short* __restrict__ w2f,
                                                 const float* __restrict__ frac,
                                                 const float* __restrict__ noise,
                                                 const float* __restrict__ pnoise,
                                                 const float* __restrict__ lattice,
                                                 const int*   __restrict__ tarr,
                                                 const float* __restrict__ sacp,
                                                 const float* __restrict__ som,
                                                 float* __restrict__ mseP,
                                                 float* __restrict__ repP,
                                                 float* __restrict__ specP) {
  __shared__ __attribute__((aligned(16))) unsigned short Hs[H_LDS_SHORTS];
  __shared__ float f[NPER*3];
  __shared__ float wred[12];
  const int tid  = threadIdx.x;
  const int wave = tid >> 6, lane = tid & 63;
  const int q = lane >> 4, l15 = lane & 15;
  const int b = blockIdx.x, atomBase = b*64, slabBase = atomBase + wave*16;

  // ---- rep/MSE prologue: pred_x0 -> f[] (fresh LDS region; barrier #1 covers) ----
  const int tt = tarr[b];
  const float sa = sacp[tt], so = som[tt];
  float msep = 0.0f;
  if (tid < NPER*3) {
    const int gi = b*(NPER*3) + tid;
    float fr = frac[gi], nz = noise[gi], p = pnoise[gi];
    float xt = sa*fr + so*nz;  xt -= floorf(xt);
    float px = (xt - so*p)/sa; px -= floorf(px);
    f[tid] = px;
    float d = p - nz; msep = d*d;
  }

  // ---- X B-frags from global (coalesced, each element read once) ----
  bf16x8 aF[2];
  {
    const float* rp = hfin + (size_t)(slabBase + l15) * NDIM;
    #pragma unroll
    for (int kk = 0; kk < 2; ++kk) {
      const float4 p = *(const float4*)(rp + kk*32 + q*8);
      const float4 r = *(const float4*)(rp + kk*32 + q*8 + 4);
      bf16x8 a;
      a[0]=f2bf(p.x); a[1]=f2bf(p.y); a[2]=f2bf(p.z); a[3]=f2bf(p.w);
      a[4]=f2bf(r.x); a[5]=f2bf(r.y); a[6]=f2bf(r.z); a[7]=f2bf(r.w);
      aF[kk] = a;
    }
  }

  // ---- GEMM1: D1[hidden][atom] = W1T x X^T (weights straight from global) ----
  f32x4 acc1[8];
  #pragma unroll
  for (int nt = 0; nt < 8; ++nt) acc1[nt] = (f32x4){0.f,0.f,0.f,0.f};
  #pragma unroll
  for (int nt = 0; nt < 8; ++nt) {
    #pragma unroll
    for (int kk = 0; kk < 2; ++kk) {
      bf16x8 wa = *(const bf16x8*)(w1f + (size_t)(((nt*2 + kk)*64 + lane))*8);
      acc1[nt] = __builtin_amdgcn_mfma_f32_16x16x32_bf16(wa, aF[kk], acc1[nt], 0, 0, 0);
    }
  }
  // epilogue1: +b1, SiLU, bf16, b64 store: H[atom=l15][k=nt*16+q*4+r]
  #pragma unroll
  for (int nt = 0; nt < 8; ++nt) {
    const float4 bv = *(const float4*)(b1 + nt*16 + q*4);
    float s0, s1, s2, s3;
    { float x = acc1[nt][0] + bv.x; s0 = x / (1.0f + __expf(-x)); }
    { float x = acc1[nt][1] + bv.y; s1 = x / (1.0f + __expf(-x)); }
    { float x = acc1[nt][2] + bv.z; s2 = x / (1.0f + __expf(-x)); }
    { float x = acc1[nt][3] + bv.w; s3 = x / (1.0f + __expf(-x)); }
    uint2 pk;
    pk.x = ((unsigned)(unsigned short)f2bf(s0)) | (((unsigned)(unsigned short)f2bf(s1)) << 16);
    pk.y = ((unsigned)(unsigned short)f2bf(s2)) | (((unsigned)(unsigned short)f2bf(s3)) << 16);
    *(uint2*)(Hs + (wave*16 + l15)*H_LD + nt*16 + q*4) = pk;
  }
  __syncthreads();                                    // barrier #1 (H + f ready)

  // ---- GEMM2: D2[class][atom] = W2T x H^T ----
  bf16x8 a2[4];
  #pragma unroll
  for (int kk = 0; kk < 4; ++kk)
    a2[kk] = *(const bf16x8*)(Hs + (wave*16 + l15)*H_LD + kk*32 + q*8);
  f32x4 acc2[7];
  #pragma unroll
  for (int nt = 0; nt < 7; ++nt) acc2[nt] = (f32x4){0.f,0.f,0.f,0.f};
  #pragma unroll
  for (int nt = 0; nt < 7; ++nt) {
    #pragma unroll
    for (int kk = 0; kk < 4; ++kk) {
      bf16x8 wb = *(const bf16x8*)(w2f + (size_t)(((nt*4 + kk)*64 + lane))*8);
      acc2[nt] = __builtin_amdgcn_mfma_f32_16x16x32_bf16(wb, a2[kk], acc2[nt], 0, 0, 0);
    }
  }

  // ---- log-softmax: atom = my l15 column; 28 local logits + cross-quad xor ----
  const int tgt = spec[slabBase + l15];
  float mx = -1e30f;
  #pragma unroll
  for (int nt = 0; nt < 7; ++nt) {
    float4 bb = {0.f,0.f,0.f,0.f};
    if (nt < 6 || q == 0) bb = *(const float4*)(b2 + nt*16 + q*4);  // stay in-bounds
    #pragma unroll
    for (int r = 0; r < 4; ++r) {
      const int cls = nt*16 + q*4 + r;
      float v = acc2[nt][r] + ((const float*)&bb)[r];
      v = (cls < NSPEC) ? v : -1e30f;
      acc2[nt][r] = v;
      mx = fmaxf(mx, v);
    }
  }
  mx = fmaxf(mx, __shfl_xor(mx, 16, 64));
  mx = fmaxf(mx, __shfl_xor(mx, 32, 64));
  float ssum = 0.0f, lt = 0.0f;
  #pragma unroll
  for (int nt = 0; nt < 7; ++nt) {
    #pragma unroll
    for (int r = 0; r < 4; ++r) {
      float v = acc2[nt][r];
      ssum += __expf(v - mx);
      lt   += (nt*16 + q*4 + r == tgt) ? v : 0.0f;
    }
  }
  ssum += __shfl_xor(ssum, 16, 64);  ssum += __shfl_xor(ssum, 32, 64);
  lt   += __shfl_xor(lt,   16, 64);  lt   += __shfl_xor(lt,   32, 64);
  float logp = lt - mx - __logf(ssum);           // identical across the 4 quads
  #pragma unroll
  for (int d = 1; d < 16; d <<= 1) logp += __shfl_xor(logp, d, 64);  // sum 16 atoms

  // ---- repulsion (reads f[], covered by barrier #1) ----
  const float* L = lattice + b*9;                // wave-uniform -> scalar loads
  const float L00=L[0],L01=L[1],L02=L[2],
              L10=L[3],L11=L[4],L12=L[5],
              L20=L[6],L21=L[7],L22=L[8];
  float rep = 0.0f;
  #pragma unroll 4
  for (int it = 0; it < 16; ++it) {
    const int i = it*4 + wave;                   // wave-uniform (broadcast reads)
    const int j = lane;                          // stride-3 -> 2-way (free)
    if (i != j) {
      float dx = f[i*3+0] - f[j*3+0]; dx -= rintf(dx);
      float dy = f[i*3+1] - f[j*3+1]; dy -= rintf(dy);
      float dz = f[i*3+2] - f[j*3+2]; dz -= rintf(dz);
      float cx = dx*L00 + dy*L10 + dz*L20;
      float cy = dx*L01 + dy*L11 + dz*L21;
      float cz = dx*L02 + dy*L12 + dz*L22;
      float dist = sqrtf(cx*cx + cy*cy + cz*cz + 1e-8f);
      float r = 0.8f - dist;
      if (r > 0.0f) rep = fmaf(r, r, rep);
    }
  }
  #pragma unroll
  for (int o = 32; o > 0; o >>= 1) {
    rep  += __shfl_down(rep,  o, 64);
    msep += __shfl_down(msep, o, 64);
  }
  if (lane == 0) { wred[wave] = logp; wred[4+wave] = rep; wred[8+wave] = msep; }
  __syncthreads();                                    // barrier #2
  if (tid == 0) {
    specP[b] = wred[0] + wred[1] + wred[2]  + wred[3];
    repP[b]  = wred[4] + wred[5] + wred[6]  + wred[7];
    mseP[b]  = wred[8] + wred[9] + wred[10] + wred[11];
  }
}

// ---------------------------------------------------------------------------
// K3: deterministic fp64 reduction of per-block partials -> 3 scalars.
// ---------------------------------------------------------------------------
__global__ __launch_bounds__(1024) void k_fin(const float* __restrict__ mseP,
                                              const float* __restrict__ repP,
                                              const float* __restrict__ specP,
                                              float* __restrict__ out) {
  __shared__ double sh[48];
  const int tid = threadIdx.x;
  double m = 0.0, r = 0.0, s = 0.0;
  for (int i = tid; i < NB; i += 1024) {
    m += (double)mseP[i];
    r += (double)repP[i];
    s += (double)specP[i];
  }
  #pragma unroll
  for (int o = 32; o > 0; o >>= 1) {
    m += __shfl_down(m, o, 64);
    r += __shfl_down(r, o, 64);
    s += __shfl_down(s, o, 64);
  }
  const int w = tid >> 6, lane = tid & 63;
  if (lane == 0) { sh[w] = m; sh[16+w] = r; sh[32+w] = s; }
  __syncthreads();
  if (tid == 0) {
    double M=0, R=0, S=0;
    for (int i = 0; i < 16; ++i) { M += sh[i]; R += sh[16+i]; S += sh[32+i]; }
    double mse   = M / (double)(NATOMS*3);
    double lrep  = R / (double)NATOMS;
    double lspec = -S / (double)NATOMS;
    out[0] = (float)(mse + 5.0*lrep);
    out[1] = (float)lspec;
    out[2] = (float)lrep;
  }
}

extern "C" void kernel_launch(void* const* d_in, const int* in_sizes, int n_in,
                              void* d_out, int out_size, void* d_ws, size_t ws_size,
                              hipStream_t stream) {
  const float* frac    = (const float*)d_in[0];
  const float* noise   = (const float*)d_in[1];
  const float* pnoise  = (const float*)d_in[2];
  const float* hfin    = (const float*)d_in[3];
  const float* lattice = (const float*)d_in[4];
  const float* W1      = (const float*)d_in[5];
  const float* b1      = (const float*)d_in[6];
  const float* W2      = (const float*)d_in[7];
  const float* b2      = (const float*)d_in[8];
  const int*   tarr    = (const int*)d_in[9];
  const int*   spec    = (const int*)d_in[11];
  float* out = (float*)d_out;

  // ws layout: [0,4K) sacp | [4K,8K) som | [8K,24K) w1f frag | [24K,52K) w2f frag
  //            [52K,+8K) mseP | [60K,+8K) repP | [68K,+8K) specP
  float*  sacp = (float*)d_ws;
  float*  som  = sacp + 1024;
  unsigned short* w1f = (unsigned short*)((char*)d_ws + 8192);
  unsigned short* w2f = (unsigned short*)((char*)d_ws + 24576);
  float* mseP  = (float*)((char*)d_ws + 53248);
  float* repP  = (float*)((char*)d_ws + 61440);
  float* specP = (float*)((char*)d_ws + 69632);

  k_sched<<<dim3(12), dim3(256),  0, stream>>>(sacp, som, W1, W2, w1f, w2f);
  k_main <<<dim3(NB), dim3(256),  0, stream>>>(hfin, b1, b2, spec, w1f, w2f,
                                               frac, noise, pnoise, lattice,
                                               tarr, sacp, som, mseP, repP, specP);
  k_fin  <<<dim3(1),  dim3(1024), 0, stream>>>(mseP, repP, specP, out);
}

// Round 6
// 128.376 us; speedup vs baseline: 2.9001x; 1.0677x over previous
//
#include <hip/hip_runtime.h>
#include <math.h>

#define TSTEPS   1000
#define NB       2048
#define NPER     64
#define NATOMS   (NB*NPER)
#define NDIM     64
#define NHID     128
#define NSPEC    100

typedef __attribute__((ext_vector_type(8))) short bf16x8;
typedef __attribute__((ext_vector_type(4))) float f32x4;

// fp32 -> bf16 bits, round-to-nearest-even (finite inputs)
__device__ inline short f2bf(float x) {
  unsigned u = __builtin_bit_cast(unsigned, x);
  u += 0x7fffu + ((u >> 16) & 1u);
  return (short)(u >> 16);
}

// ---------------------------------------------------------------------------
// K1 (12 blocks x 256): block 0 = cosine schedule (fp64, 4 t/thread, one
// 256-wide LDS scan) + padded b2; blocks 1-4 = W1 frag image; 5-11 = W2 image.
// Fragment chunk order: k_main reads weights as coalesced 16B/lane from global.
//   w1f: A-frag W1T[m=nt*16+l15][k=kk*32+q*8+j], tile = nt*2+kk  (16 tiles)
//   w2f: A-frag W2T[cls=nt*16+l15][k=kk*32+q*8+j], tile = nt*4+kk (28 tiles)
// ---------------------------------------------------------------------------
__global__ __launch_bounds__(256) void k_sched(float* __restrict__ sacp,
                                               float* __restrict__ som,
                                               const float* __restrict__ W1,
                                               const float* __restrict__ W2,
                                               const float* __restrict__ b2,
                                               unsigned short* __restrict__ w1f,
                                               unsigned short* __restrict__ w2f,
                                               float* __restrict__ b2p) {
  const int tid = threadIdx.x, blk = blockIdx.x;
  if (blk == 0) {
    if (tid < 112) b2p[tid] = (tid < NSPEC) ? b2[tid] : 0.0f;
    __shared__ double sh[256];
    const double PI = 3.14159265358979323846, s = 0.008;
    const int t0 = tid * 4;
    double lg[4], loc = 0.0;
    if (t0 < TSTEPS) {
      double c[5];
      #pragma unroll
      for (int i = 0; i < 5; ++i) {
        double u = (((double)(t0 + i) / (double)TSTEPS) + s) / (1.0 + s) * PI * 0.5;
        c[i] = cos(u);
      }
      #pragma unroll
      for (int i = 0; i < 4; ++i) {
        double beta = 1.0 - (c[i+1]*c[i+1]) / (c[i]*c[i]);
        beta = fmin(fmax(beta, 1e-4), 0.999);
        lg[i] = log(1.0 - beta);
        loc += lg[i];
      }
    }
    sh[tid] = loc;
    __syncthreads();
    for (int off = 1; off < 256; off <<= 1) {     // inclusive scan of per-thread sums
      double add = (tid >= off) ? sh[tid - off] : 0.0;
      __syncthreads();
      sh[tid] += add;
      __syncthreads();
    }
    if (t0 < TSTEPS) {
      double run = sh[tid] - loc;                 // exclusive prefix
      #pragma unroll
      for (int i = 0; i < 4; ++i) {
        run += lg[i];
        double cum = exp(run);                    // alphas_cumprod[t0+i]
        sacp[t0+i] = (float)sqrt(cum);
        som[t0+i]  = (float)sqrt(1.0 - cum);
      }
    }
  } else if (blk <= 4) {
    const int c0 = (blk - 1) * 256 + tid;         // chunk in [0,1024)
    const int lane = c0 & 63, t = c0 >> 6;        // t in [0,16)
    const int kk = t & 1, nt = t >> 1;
    const int q = lane >> 4, l15 = lane & 15;
    __attribute__((aligned(16))) unsigned short v[8];
    #pragma unroll
    for (int j = 0; j < 8; ++j) {
      int k = kk*32 + q*8 + j;
      v[j] = (unsigned short)f2bf(W1[k*NHID + nt*16 + l15]);
    }
    *(uint4*)(w1f + (size_t)c0*8) = *(const uint4*)v;
  } else {
    for (int c0 = (blk - 5) * 256 + tid; c0 < 3584; c0 += 1792) {  // 28 tiles
      const int lane = c0 & 63, t = c0 >> 6;      // t in [0,56)
      const int kk = t & 3, nt = t >> 2;
      const int q = lane >> 4, l15 = lane & 15;
      const int cls = nt*16 + l15;
      __attribute__((aligned(16))) unsigned short v[8];
      #pragma unroll
      for (int j = 0; j < 8; ++j) {
        int k = kk*32 + q*8 + j;
        v[j] = (cls < NSPEC) ? (unsigned short)f2bf(W2[k*NSPEC + cls]) : 0;
      }
      *(uint4*)(w2f + (size_t)c0*8) = *(const uint4*)v;
    }
  }
}

// ---------------------------------------------------------------------------
// K2: fused species head + repulsion + MSE. Block = 1 crystal, 256 threads.
// ZERO __syncthreads: H round-trip is wave-local LDS (DS in-order per wave),
// rep atoms live in registers (one atom/lane, i-rows via uniform shfl), and
// per-wave partials go straight to workspace. Occupancy is register-capped
// (~100 V+AGPR/wave -> ~5 waves/SIMD), so the optimization target is VALU
// instruction count: rcpf/sqrt fast intrinsics throughout.
// ---------------------------------------------------------------------------
__global__ __launch_bounds__(256) void k_main(const float* __restrict__ hfin,
                                              const float* __restrict__ b1,
                                              const float* __restrict__ b2p,
                                              const int*   __restrict__ spec,
                                              const unsigned short* __restrict__ w1f,
                                              const unsigned short* __restrict__ w2f,
                                              const float* __restrict__ frac,
                                              const float* __restrict__ noise,
                                              const float* __restrict__ pnoise,
                                              const float* __restrict__ lattice,
                                              const int*   __restrict__ tarr,
                                              const float* __restrict__ sacp,
                                              const float* __restrict__ som,
                                              float* __restrict__ mseP,
                                              float* __restrict__ repP,
                                              float* __restrict__ specP) {
  // per-wave H region: 2048 shorts, chunk layout: addr(a=l15, h) =
  //   (h>>3)*128 + a*8 + (h&7)   -> b64 writes, linear b128 reads, no conflicts
  __shared__ __attribute__((aligned(16))) unsigned short Hs[4*2048];
  const int tid  = threadIdx.x;
  const int wave = tid >> 6, lane = tid & 63;
  const int q = lane >> 4, l15 = lane & 15;
  const int b = blockIdx.x, atomBase = b*64, slabBase = atomBase + wave*16;
  unsigned short* HsW = Hs + wave*2048;

  // ---- rep/MSE prologue: one atom per lane, all in registers ----
  const int tt = tarr[b];
  const float sa = sacp[tt], so = som[tt];
  const float rsa = __builtin_amdgcn_rcpf(sa);
  float px0, px1, px2, msep;
  {
    const int a = atomBase + lane;
    const float3 fr = *(const float3*)(frac   + 3*(size_t)a);
    const float3 nz = *(const float3*)(noise  + 3*(size_t)a);
    const float3 pn = *(const float3*)(pnoise + 3*(size_t)a);
    float xt0 = fmaf(so, nz.x, sa*fr.x); xt0 -= floorf(xt0);
    float xt1 = fmaf(so, nz.y, sa*fr.y); xt1 -= floorf(xt1);
    float xt2 = fmaf(so, nz.z, sa*fr.z); xt2 -= floorf(xt2);
    px0 = (xt0 - so*pn.x)*rsa; px0 -= floorf(px0);
    px1 = (xt1 - so*pn.y)*rsa; px1 -= floorf(px1);
    px2 = (xt2 - so*pn.z)*rsa; px2 -= floorf(px2);
    float d0 = pn.x - nz.x, d1 = pn.y - nz.y, d2 = pn.z - nz.z;
    msep = fmaf(d0, d0, fmaf(d1, d1, d2*d2));
  }

  // ---- X B-frags from global (coalesced, each element read once) ----
  bf16x8 aF[2];
  {
    const float* rp = hfin + (size_t)(slabBase + l15) * NDIM;
    #pragma unroll
    for (int kk = 0; kk < 2; ++kk) {
      const float4 p = *(const float4*)(rp + kk*32 + q*8);
      const float4 r = *(const float4*)(rp + kk*32 + q*8 + 4);
      bf16x8 a;
      a[0]=f2bf(p.x); a[1]=f2bf(p.y); a[2]=f2bf(p.z); a[3]=f2bf(p.w);
      a[4]=f2bf(r.x); a[5]=f2bf(r.y); a[6]=f2bf(r.z); a[7]=f2bf(r.w);
      aF[kk] = a;
    }
  }

  // ---- GEMM1: D1[hidden][atom] = W1T(A) x X^T(B), weights from global ----
  f32x4 acc1[8];
  #pragma unroll
  for (int nt = 0; nt < 8; ++nt) acc1[nt] = (f32x4){0.f,0.f,0.f,0.f};
  #pragma unroll
  for (int nt = 0; nt < 8; ++nt) {
    #pragma unroll
    for (int kk = 0; kk < 2; ++kk) {
      bf16x8 wa = *(const bf16x8*)(w1f + (size_t)(((nt*2 + kk)*64 + lane))*8);
      acc1[nt] = __builtin_amdgcn_mfma_f32_16x16x32_bf16(wa, aF[kk], acc1[nt], 0, 0, 0);
    }
  }
  // epilogue1: +b1, fast SiLU, bf16, b64 store into per-wave chunk layout:
  //   h = nt*16+q*4+r  ->  off = (nt*2+(q>>1))*128 + l15*8 + (q&1)*4
  #pragma unroll
  for (int nt = 0; nt < 8; ++nt) {
    const float4 bv = *(const float4*)(b1 + nt*16 + q*4);
    float sl[4];
    #pragma unroll
    for (int r = 0; r < 4; ++r) {
      float x = acc1[nt][r] + ((const float*)&bv)[r];
      float e = __expf(-x);
      sl[r] = x * __builtin_amdgcn_rcpf(1.0f + e);
    }
    uint2 pk;
    pk.x = ((unsigned)(unsigned short)f2bf(sl[0])) | (((unsigned)(unsigned short)f2bf(sl[1])) << 16);
    pk.y = ((unsigned)(unsigned short)f2bf(sl[2])) | (((unsigned)(unsigned short)f2bf(sl[3])) << 16);
    *(uint2*)(HsW + (nt*2 + (q>>1))*128 + l15*8 + (q&1)*4) = pk;
  }
  __builtin_amdgcn_wave_barrier();   // pin compiler order; DS is in-order per wave

  // ---- GEMM2: D2[class][atom] = W2T(A) x H^T(B) ----
  bf16x8 a2[4];
  #pragma unroll
  for (int kk = 0; kk < 4; ++kk)
    a2[kk] = *(const bf16x8*)(HsW + (kk*4 + q)*128 + l15*8);
  f32x4 acc2[7];
  #pragma unroll
  for (int nt = 0; nt < 7; ++nt) acc2[nt] = (f32x4){0.f,0.f,0.f,0.f};
  #pragma unroll
  for (int nt = 0; nt < 7; ++nt) {
    #pragma unroll
    for (int kk = 0; kk < 4; ++kk) {
      bf16x8 wb = *(const bf16x8*)(w2f + (size_t)(((nt*4 + kk)*64 + lane))*8);
      acc2[nt] = __builtin_amdgcn_mfma_f32_16x16x32_bf16(wb, a2[kk], acc2[nt], 0, 0, 0);
    }
  }

  // ---- log-softmax: atom = l15 column; 28 local logits, cross-quad xor ----
  const int tgt = spec[slabBase + l15];
  float mx = -1e30f;
  #pragma unroll
  for (int nt = 0; nt < 7; ++nt) {
    const float4 bb = *(const float4*)(b2p + nt*16 + q*4);
    #pragma unroll
    for (int r = 0; r < 4; ++r) {
      const int cls = nt*16 + q*4 + r;
      float v = acc2[nt][r] + ((const float*)&bb)[r];
      v = (cls < NSPEC) ? v : -1e30f;
      acc2[nt][r] = v;
      mx = fmaxf(mx, v);
    }
  }
  mx = fmaxf(mx, __shfl_xor(mx, 16, 64));
  mx = fmaxf(mx, __shfl_xor(mx, 32, 64));
  float ssum = 0.0f, lt = 0.0f;
  #pragma unroll
  for (int nt = 0; nt < 7; ++nt) {
    #pragma unroll
    for (int r = 0; r < 4; ++r) {
      float v = acc2[nt][r];
      ssum += __expf(v - mx);
      lt   += (nt*16 + q*4 + r == tgt) ? v : 0.0f;
    }
  }
  ssum += __shfl_xor(ssum, 16, 64);  ssum += __shfl_xor(ssum, 32, 64);
  lt   += __shfl_xor(lt,   16, 64);  lt   += __shfl_xor(lt,   32, 64);
  float logp = lt - mx - __logf(ssum);            // identical across 4 quads
  #pragma unroll
  for (int d = 1; d < 16; d <<= 1) logp += __shfl_xor(logp, d, 64);  // 16-atom sum

  // ---- repulsion: wave w owns i in [w*16, w*16+16), j = lane's atom ----
  const float* L = lattice + b*9;                 // uniform -> scalar loads
  const float L00=L[0],L01=L[1],L02=L[2],
              L10=L[3],L11=L[4],L12=L[5],
              L20=L[6],L21=L[7],L22=L[8];
  float rep = 0.0f;
  #pragma unroll
  for (int it = 0; it < 16; ++it) {
    const int i = wave*16 + it;                   // wave-uniform
    float xi = __shfl(px0, i, 64);
    float yi = __shfl(px1, i, 64);
    float zi = __shfl(px2, i, 64);
    if (i != lane) {
      float dx = xi - px0; dx -= rintf(dx);       // minimum image
      float dy = yi - px1; dy -= rintf(dy);
      float dz = zi - px2; dz -= rintf(dz);
      float cx = dx*L00 + dy*L10 + dz*L20;
      float cy = dx*L01 + dy*L11 + dz*L21;
      float cz = dx*L02 + dy*L12 + dz*L22;
      float d2 = fmaf(cx, cx, fmaf(cy, cy, cz*cz)) + 1e-8f;
      float r  = 0.8f - __builtin_amdgcn_sqrtf(d2);   // single v_sqrt_f32
      if (r > 0.0f) rep = fmaf(r, r, rep);
    }
  }
  #pragma unroll
  for (int o = 32; o > 0; o >>= 1) {
    rep  += __shfl_down(rep,  o, 64);
    msep += __shfl_down(msep, o, 64);
  }
  if (lane == 0) {
    specP[b*4 + wave] = logp;
    repP [b*4 + wave] = rep;
    if (wave == 0) mseP[b] = msep;                // each wave holds all 64 atoms
  }
}

// ---------------------------------------------------------------------------
// K3: deterministic fp64 reduction of per-wave partials -> 3 scalars.
// ---------------------------------------------------------------------------
__global__ __launch_bounds__(1024) void k_fin(const float* __restrict__ mseP,
                                              const float* __restrict__ repP,
                                              const float* __restrict__ specP,
                                              float* __restrict__ out) {
  __shared__ double sh[48];
  const int tid = threadIdx.x;
  double m = 0.0, r = 0.0, s = 0.0;
  for (int i = tid; i < NB*4; i += 1024) {
    r += (double)repP[i];
    s += (double)specP[i];
    if (i < NB) m += (double)mseP[i];
  }
  #pragma unroll
  for (int o = 32; o > 0; o >>= 1) {
    m += __shfl_down(m, o, 64);
    r += __shfl_down(r, o, 64);
    s += __shfl_down(s, o, 64);
  }
  const int w = tid >> 6, lane = tid & 63;
  if (lane == 0) { sh[w] = m; sh[16+w] = r; sh[32+w] = s; }
  __syncthreads();
  if (tid == 0) {
    double M=0, R=0, S=0;
    for (int i = 0; i < 16; ++i) { M += sh[i]; R += sh[16+i]; S += sh[32+i]; }
    double mse   = M / (double)(NATOMS*3);
    double lrep  = R / (double)NATOMS;
    double lspec = -S / (double)NATOMS;
    out[0] = (float)(mse + 5.0*lrep);
    out[1] = (float)lspec;
    out[2] = (float)lrep;
  }
}

extern "C" void kernel_launch(void* const* d_in, const int* in_sizes, int n_in,
                              void* d_out, int out_size, void* d_ws, size_t ws_size,
                              hipStream_t stream) {
  const float* frac    = (const float*)d_in[0];
  const float* noise   = (const float*)d_in[1];
  const float* pnoise  = (const float*)d_in[2];
  const float* hfin    = (const float*)d_in[3];
  const float* lattice = (const float*)d_in[4];
  const float* W1      = (const float*)d_in[5];
  const float* b1      = (const float*)d_in[6];
  const float* W2      = (const float*)d_in[7];
  const float* b2      = (const float*)d_in[8];
  const int*   tarr    = (const int*)d_in[9];
  const int*   spec    = (const int*)d_in[11];
  float* out = (float*)d_out;

  // ws: [0,4K) sacp | [4K,8K) som | [8K,24K) w1f | [24K,52K) w2f
  //     [52K,+512) b2p | [53760,+8K) mseP | [61952,+32K) repP | [94720,+32K) specP
  float*  sacp = (float*)d_ws;
  float*  som  = sacp + 1024;
  unsigned short* w1f = (unsigned short*)((char*)d_ws + 8192);
  unsigned short* w2f = (unsigned short*)((char*)d_ws + 24576);
  float* b2p   = (float*)((char*)d_ws + 53248);
  float* mseP  = (float*)((char*)d_ws + 53760);
  float* repP  = (float*)((char*)d_ws + 61952);
  float* specP = (float*)((char*)d_ws + 94720);

  k_sched<<<dim3(12), dim3(256),  0, stream>>>(sacp, som, W1, W2, b2, w1f, w2f, b2p);
  k_main <<<dim3(NB), dim3(256),  0, stream>>>(hfin, b1, b2p, spec, w1f, w2f,
                                               frac, noise, pnoise, lattice,
                                               tarr, sacp, som, mseP, repP, specP);
  k_fin  <<<dim3(1),  dim3(1024), 0, stream>>>(mseP, repP, specP, out);
}